// Round 28
// baseline (23.038 us; speedup 1.0000x reference)
//
#include <hip/hip_runtime.h>

// L=32768, N=32, E=H=1, BS=256 -> 4096 rank-1 softmax problems:
//   out_i = sum_j 2^(a'_i k_j) v_j / sum_j 2^(a'_i k_j),  a' = (wq q + bq) log2e.
// No max-subtraction (f32-safe, scale-invariant; validated R5-R27).
//
// R28 = R27 (22.9us) testing the WG-SLOT occupancy hypothesis: with 1-wave
// WGs, 4096 WGs/256 CU = 16 WGs/CU; if the CU's resident-WG slots (~16) are
// the binder, we're stuck at 16 waves/CU regardless of LDS/VGPR headroom.
// Fix: TWO fully-INDEPENDENT waves per WG (2048 WGs x 128 thr): each wave
// runs the complete R23 pipeline in its own LDS region -- no shared state,
// no barriers, zero coupling (unlike R17/R20/R24 which shared the sort and
// lost). Pairing (blk,n) with (blk,n+16): same blk -> same co-located XCD L2
// for both gathers (R26 win preserved) + same output lines (R23 write-merge).

#define LL    32768
#define NN    32
#define BSZ   256
#define NBLK  (LL / BSZ)
#define NSEG  16
#define LOG2E 1.4426950408889634f
#define LN2   0.6931471805599453f

typedef float v2f __attribute__((ext_vector_type(2)));

// ---------------- Kernel P: projection + transpose (verified R3/R26) -------
// Grid 1024; WG g handles rows r0 = (g&127)*256 + (g>>7)*32 so that all 8
// chunks of block bb sit on XCD bb%8 (matches attn consumer XCD).
__global__ __launch_bounds__(256) void proj_transpose_kernel(
    const float* __restrict__ q_in, const float* __restrict__ k_in,
    const float* __restrict__ v_in,
    const float* __restrict__ ipw,  const float* __restrict__ ipb,
    float* __restrict__ ws)
{
    __shared__ float sa[32][33], sk[32][33], sv[32][33];
    const int t   = threadIdx.x;
    const int bb  = blockIdx.x & 127;   // 256-row block
    const int sub = blockIdx.x >> 7;    // 32-row chunk within block
    const int r0  = bb * 256 + sub * 32;

    const float wq = ipw[0], wk = ipw[1], wv = ipw[2];
    const float bq = ipb[0], bk = ipb[1], bv = ipb[2];

    const int f = r0 * NN + t * 4;     // coalesced: 4 consecutive n of one row
    const float4 q4 = *reinterpret_cast<const float4*>(q_in + f);
    const float4 k4 = *reinterpret_cast<const float4*>(k_in + f);
    const float4 v4 = *reinterpret_cast<const float4*>(v_in + f);

    const int row = t >> 3, nc = (t & 7) * 4;
    sa[row][nc + 0] = fmaf(q4.x, wq, bq) * LOG2E;
    sa[row][nc + 1] = fmaf(q4.y, wq, bq) * LOG2E;
    sa[row][nc + 2] = fmaf(q4.z, wq, bq) * LOG2E;
    sa[row][nc + 3] = fmaf(q4.w, wq, bq) * LOG2E;
    sk[row][nc + 0] = fmaf(k4.x, wk, bk);
    sk[row][nc + 1] = fmaf(k4.y, wk, bk);
    sk[row][nc + 2] = fmaf(k4.z, wk, bk);
    sk[row][nc + 3] = fmaf(k4.w, wk, bk);
    sv[row][nc + 0] = fmaf(v4.x, wv, bv);
    sv[row][nc + 1] = fmaf(v4.y, wv, bv);
    sv[row][nc + 2] = fmaf(v4.z, wv, bv);
    sv[row][nc + 3] = fmaf(v4.w, wv, bv);
    __syncthreads();

    float* __restrict__ A = ws;
    float* __restrict__ K = ws + (size_t)LL * NN;
    float* __restrict__ V = ws + (size_t)2 * LL * NN;
    const int n = t >> 3, j0 = (t & 7) * 4;  // coalesced: 4 consecutive rows

    float4 o;
    o.x = sa[j0 + 0][n]; o.y = sa[j0 + 1][n]; o.z = sa[j0 + 2][n]; o.w = sa[j0 + 3][n];
    *reinterpret_cast<float4*>(A + (size_t)n * LL + r0 + j0) = o;
    o.x = sk[j0 + 0][n]; o.y = sk[j0 + 1][n]; o.z = sk[j0 + 2][n]; o.w = sk[j0 + 3][n];
    *reinterpret_cast<float4*>(K + (size_t)n * LL + r0 + j0) = o;
    o.x = sv[j0 + 0][n]; o.y = sv[j0 + 1][n]; o.z = sv[j0 + 2][n]; o.w = sv[j0 + 3][n];
    *reinterpret_cast<float4*>(V + (size_t)n * LL + r0 + j0) = o;
}

__device__ __forceinline__ v2f horner7(v2f u, float4 f0, float4 f1) {
    v2f h = {f1.w, f1.w};
    h = __builtin_elementwise_fma(h, u, (v2f){f1.z, f1.z});
    h = __builtin_elementwise_fma(h, u, (v2f){f1.y, f1.y});
    h = __builtin_elementwise_fma(h, u, (v2f){f1.x, f1.x});
    h = __builtin_elementwise_fma(h, u, (v2f){f0.w, f0.w});
    h = __builtin_elementwise_fma(h, u, (v2f){f0.z, f0.z});
    h = __builtin_elementwise_fma(h, u, (v2f){f0.y, f0.y});
    h = __builtin_elementwise_fma(h, u, (v2f){f0.x, f0.x});
    return h;
}

// -------- Kernel A: 2 INDEPENDENT waves per WG, private LDS, no barriers ----
__global__ __launch_bounds__(128) void attn_kernel(
    const float* __restrict__ ws,
    const float* __restrict__ opw, const float* __restrict__ opb,
    float* __restrict__ out)
{
    const int lane = threadIdx.x & 63;
    const int wid  = threadIdx.x >> 6;       // wave 0/1: independent problems
    const int prob = blockIdx.x + wid * 2048; // pair (blk,n) and (blk,n+16)
    const int blk  = prob & 127;             // XCD-aware (R23/R26-verified)
    const int n    = prob >> 7;

    const float* __restrict__ A = ws;
    const float* __restrict__ K = ws + (size_t)LL * NN;
    const float* __restrict__ V = ws + (size_t)2 * LL * NN;
    const int base = n * LL + blk * BSZ;

    __shared__ alignas(16) float2 skv[2][BSZ];       // per-wave private
    __shared__ alignas(16) float  mom[2][NSEG][16];
    __shared__ int hist[2][128];

    // ---- gather: k,v first (sort-critical), a stays in flight ----
    const float4 kf = *reinterpret_cast<const float4*>(K + base + 4 * lane);
    const float4 vf = *reinterpret_cast<const float4*>(V + base + 4 * lane);
    const float4 af = *reinterpret_cast<const float4*>(A + base + 4 * lane);
    float kr[4] = {kf.x, kf.y, kf.z, kf.w};
    float vr[4] = {vf.x, vf.y, vf.z, vf.w};

    // wave kmin/kmax
    float kmn = fminf(fminf(kr[0], kr[1]), fminf(kr[2], kr[3]));
    float kmx = fmaxf(fmaxf(kr[0], kr[1]), fmaxf(kr[2], kr[3]));
    #pragma unroll
    for (int off = 32; off >= 1; off >>= 1) {
        kmn = fminf(kmn, __shfl_xor(kmn, off));
        kmx = fmaxf(kmx, __shfl_xor(kmx, off));
    }
    const float rng  = kmx - kmn;
    const float binv = (rng > 0.f) ? (127.99f / rng) : 0.f;
    const float segw = rng * (1.0f / NSEG);

    // ---- counting sort (wave-private LDS, program order, no barriers) ----
    hist[wid][lane]      = 0;
    hist[wid][lane + 64] = 0;

    int bin[4];
    #pragma unroll
    for (int r = 0; r < 4; ++r) {
        int b = (int)((kr[r] - kmn) * binv);
        bin[r] = (b < 0) ? 0 : ((b > 127) ? 127 : b);
        atomicAdd(&hist[wid][bin[r]], 1);    // wave-private, lane-ordered
    }

    {
        const int c0 = hist[wid][lane];
        const int c1 = hist[wid][lane + 64];
        int i0 = c0, i1 = c1;
        #pragma unroll
        for (int off = 1; off <= 32; off <<= 1) {
            const int t0 = __shfl_up(i0, off);
            const int t1 = __shfl_up(i1, off);
            if (lane >= off) { i0 += t0; i1 += t1; }
        }
        const int tot0 = __shfl(i0, 63);
        hist[wid][lane]      = i0 - c0;      // exclusive starts
        hist[wid][lane + 64] = i1 - c1 + tot0;
    }

    #pragma unroll
    for (int r = 0; r < 4; ++r) {
        const int slot = atomicAdd(&hist[wid][bin[r]], 1);
        skv[wid][slot] = make_float2(kr[r], vr[r]);
    }
    // hist[wid][b] = END offset of bin b

    // ---- moments: 4 lanes per segment (contiguous quarter-ranges) ----
    {
        const int s  = lane >> 2;           // segment 0..15
        const int qq = lane & 3;            // quarter 0..3
        const int beg0 = (s == 0) ? 0 : hist[wid][8 * s - 1];
        const int end0 = hist[wid][8 * s + 7];
        const int len  = end0 - beg0;
        const int beg  = beg0 + (len * qq) / 4;
        const int end  = beg0 + (len * (qq + 1)) / 4;
        const float cs = kmn + (s + 0.5f) * segw;

        float m0=0.f,m1=0.f,m2=0.f,m3=0.f,m4=0.f,m5=0.f,m6=0.f,m7=0.f;
        float q0=0.f,q1=0.f,q2=0.f,q3=0.f,q4=0.f,q5=0.f,q6=0.f,q7=0.f;
        for (int e = beg; e < end; ++e) {
            const float2 kv = skv[wid][e];
            const float dk = kv.x - cs;
            const float vv = kv.y;
            const float p1 = dk,      p2 = p1 * dk, p3 = p2 * dk;
            const float p4 = p3 * dk, p5 = p4 * dk, p6 = p5 * dk, p7 = p6 * dk;
            m0 += 1.f; m1 += p1; m2 += p2; m3 += p3;
            m4 += p4;  m5 += p5; m6 += p6; m7 += p7;
            q0 += vv;
            q1 = fmaf(vv, p1, q1); q2 = fmaf(vv, p2, q2); q3 = fmaf(vv, p3, q3);
            q4 = fmaf(vv, p4, q4); q5 = fmaf(vv, p5, q5); q6 = fmaf(vv, p6, q6);
            q7 = fmaf(vv, p7, q7);
        }
        // combine 4 quarters (lanes 4s..4s+3)
        #pragma unroll
        for (int off = 1; off <= 2; off <<= 1) {
            m0 += __shfl_xor(m0, off); m1 += __shfl_xor(m1, off);
            m2 += __shfl_xor(m2, off); m3 += __shfl_xor(m3, off);
            m4 += __shfl_xor(m4, off); m5 += __shfl_xor(m5, off);
            m6 += __shfl_xor(m6, off); m7 += __shfl_xor(m7, off);
            q0 += __shfl_xor(q0, off); q1 += __shfl_xor(q1, off);
            q2 += __shfl_xor(q2, off); q3 += __shfl_xor(q3, off);
            q4 += __shfl_xor(q4, off); q5 += __shfl_xor(q5, off);
            q6 += __shfl_xor(q6, off); q7 += __shfl_xor(q7, off);
        }
        float4 wv4;
        if (qq == 0)      wv4 = make_float4(m0, m1, m2 * 0.5f, m3 * (1.f/6.f));
        else if (qq == 1) wv4 = make_float4(m4 * (1.f/24.f), m5 * (1.f/120.f),
                                            m6 * (1.f/720.f), m7 * (1.f/5040.f));
        else if (qq == 2) wv4 = make_float4(q0, q1, q2 * 0.5f, q3 * (1.f/6.f));
        else              wv4 = make_float4(q4 * (1.f/24.f), q5 * (1.f/120.f),
                                            q6 * (1.f/720.f), q7 * (1.f/5040.f));
        *reinterpret_cast<float4*>(&mom[wid][s][qq * 4]) = wv4;
    }

    // ---- row loop: 4 rows/thread, E-recurrence (2 chains), deg-7 Horner ----
    const float a[4] = {af.x, af.y, af.z, af.w};   // already * LOG2E
    const v2f u01 = {a[0] * LN2, a[1] * LN2};
    const v2f u23 = {a[2] * LN2, a[3] * LN2};
    const float c0s = kmn + 0.5f * segw;

    v2f Ee01, Ee23, g01, g23;
    Ee01.x = __builtin_amdgcn_exp2f(a[0] * c0s);
    Ee01.y = __builtin_amdgcn_exp2f(a[1] * c0s);
    Ee23.x = __builtin_amdgcn_exp2f(a[2] * c0s);
    Ee23.y = __builtin_amdgcn_exp2f(a[3] * c0s);
    g01.x  = __builtin_amdgcn_exp2f(a[0] * segw);
    g01.y  = __builtin_amdgcn_exp2f(a[1] * segw);
    g23.x  = __builtin_amdgcn_exp2f(a[2] * segw);
    g23.y  = __builtin_amdgcn_exp2f(a[3] * segw);
    const v2f G2_01 = g01 * g01;
    const v2f G2_23 = g23 * g23;
    v2f Eo01 = Ee01 * g01;
    v2f Eo23 = Ee23 * g23;

    v2f de01 = {0.f,0.f}, do01 = {0.f,0.f}, de23 = {0.f,0.f}, do23 = {0.f,0.f};
    v2f ne01 = {0.f,0.f}, no01 = {0.f,0.f}, ne23 = {0.f,0.f}, no23 = {0.f,0.f};

    const float4* __restrict__ M4 = (const float4*)&mom[wid][0][0];

    #pragma unroll 4
    for (int s = 0; s < NSEG; s += 2) {
        {   // even segment
            const float4 f0 = M4[s * 4 + 0];
            const float4 f1 = M4[s * 4 + 1];
            const float4 f2 = M4[s * 4 + 2];
            const float4 f3 = M4[s * 4 + 3];
            const v2f hd01 = horner7(u01, f0, f1);
            const v2f hn01 = horner7(u01, f2, f3);
            const v2f hd23 = horner7(u23, f0, f1);
            const v2f hn23 = horner7(u23, f2, f3);
            de01 = __builtin_elementwise_fma(Ee01, hd01, de01);
            ne01 = __builtin_elementwise_fma(Ee01, hn01, ne01);
            de23 = __builtin_elementwise_fma(Ee23, hd23, de23);
            ne23 = __builtin_elementwise_fma(Ee23, hn23, ne23);
            Ee01 = Ee01 * G2_01;
            Ee23 = Ee23 * G2_23;
        }
        {   // odd segment
            const float4 f0 = M4[(s + 1) * 4 + 0];
            const float4 f1 = M4[(s + 1) * 4 + 1];
            const float4 f2 = M4[(s + 1) * 4 + 2];
            const float4 f3 = M4[(s + 1) * 4 + 3];
            const v2f hd01 = horner7(u01, f0, f1);
            const v2f hn01 = horner7(u01, f2, f3);
            const v2f hd23 = horner7(u23, f0, f1);
            const v2f hn23 = horner7(u23, f2, f3);
            do01 = __builtin_elementwise_fma(Eo01, hd01, do01);
            no01 = __builtin_elementwise_fma(Eo01, hn01, no01);
            do23 = __builtin_elementwise_fma(Eo23, hd23, do23);
            no23 = __builtin_elementwise_fma(Eo23, hn23, no23);
            Eo01 = Eo01 * G2_01;
            Eo23 = Eo23 * G2_23;
        }
    }

    const v2f den01 = de01 + do01, den23 = de23 + do23;
    const v2f num01 = ne01 + no01, num23 = ne23 + no23;

    const float wo = opw[0], bo = opb[0];
    const int rbase = blk * BSZ + 4 * lane;
    out[(size_t)(rbase + 0) * NN + n] = fmaf(num01.x / den01.x, wo, bo);
    out[(size_t)(rbase + 1) * NN + n] = fmaf(num01.y / den01.y, wo, bo);
    out[(size_t)(rbase + 2) * NN + n] = fmaf(num23.x / den23.x, wo, bo);
    out[(size_t)(rbase + 3) * NN + n] = fmaf(num23.y / den23.y, wo, bo);
}

extern "C" void kernel_launch(void* const* d_in, const int* in_sizes, int n_in,
                              void* d_out, int out_size, void* d_ws, size_t ws_size,
                              hipStream_t stream) {
    const float* q   = (const float*)d_in[0];
    const float* k   = (const float*)d_in[1];
    const float* v   = (const float*)d_in[2];
    const float* ipw = (const float*)d_in[3];
    const float* ipb = (const float*)d_in[4];
    const float* opw = (const float*)d_in[5];
    const float* opb = (const float*)d_in[6];
    float* out = (float*)d_out;
    float* ws  = (float*)d_ws;   // needs 3*L*N*4 = 12.6 MB

    proj_transpose_kernel<<<dim3(LL / 32), dim3(256), 0, stream>>>(q, k, v, ipw, ipb, ws);
    attn_kernel<<<dim3(NBLK * NN / 2), dim3(128), 0, stream>>>(ws, opw, opb, out);
}

// Round 29
// 21.783 us; speedup vs baseline: 1.0576x; 1.0576x over previous
//
#include <hip/hip_runtime.h>

// L=32768, N=32, E=H=1, BS=256 -> 4096 rank-1 softmax problems:
//   out_i = sum_j 2^(a'_i k_j) v_j / sum_j 2^(a'_i k_j),  a' = (wq q + bq) log2e.
// No max-subtraction (f32-safe, scale-invariant; validated R5-R28).
//
// R29 = R27 (22.9us-class best, zero-barrier single-wave attn, XCD-co-located
// prepass) with NSEG 16->8 + deg-10 Horner: row-loop LDS reads 64->48 b128,
// v2f-FMA 512->352, E-chain 16->8, moment segments 8 lanes each (contiguous
// eighth-ranges). |u*dk| <= ~2.5 worst-case -> deg-10 tail < 6e-4 rel.
// Decision experiment: a ~30% issue cut in the dominant phase; if attn is
// unmoved, its time is not issue-determined and R26 is the practical floor.

#define LL    32768
#define NN    32
#define BSZ   256
#define NBLK  (LL / BSZ)
#define NSEG  8
#define LOG2E 1.4426950408889634f
#define LN2   0.6931471805599453f

typedef float v2f __attribute__((ext_vector_type(2)));

// ---------------- Kernel P: projection + transpose (verified R3/R26) -------
// Grid 1024; WG g handles rows r0 = (g&127)*256 + (g>>7)*32 so all 8 chunks
// of block bb sit on XCD bb%8 (matches attn consumer XCD).
__global__ __launch_bounds__(256) void proj_transpose_kernel(
    const float* __restrict__ q_in, const float* __restrict__ k_in,
    const float* __restrict__ v_in,
    const float* __restrict__ ipw,  const float* __restrict__ ipb,
    float* __restrict__ ws)
{
    __shared__ float sa[32][33], sk[32][33], sv[32][33];
    const int t   = threadIdx.x;
    const int bb  = blockIdx.x & 127;   // 256-row block
    const int sub = blockIdx.x >> 7;    // 32-row chunk within block
    const int r0  = bb * 256 + sub * 32;

    const float wq = ipw[0], wk = ipw[1], wv = ipw[2];
    const float bq = ipb[0], bk = ipb[1], bv = ipb[2];

    const int f = r0 * NN + t * 4;     // coalesced: 4 consecutive n of one row
    const float4 q4 = *reinterpret_cast<const float4*>(q_in + f);
    const float4 k4 = *reinterpret_cast<const float4*>(k_in + f);
    const float4 v4 = *reinterpret_cast<const float4*>(v_in + f);

    const int row = t >> 3, nc = (t & 7) * 4;
    sa[row][nc + 0] = fmaf(q4.x, wq, bq) * LOG2E;
    sa[row][nc + 1] = fmaf(q4.y, wq, bq) * LOG2E;
    sa[row][nc + 2] = fmaf(q4.z, wq, bq) * LOG2E;
    sa[row][nc + 3] = fmaf(q4.w, wq, bq) * LOG2E;
    sk[row][nc + 0] = fmaf(k4.x, wk, bk);
    sk[row][nc + 1] = fmaf(k4.y, wk, bk);
    sk[row][nc + 2] = fmaf(k4.z, wk, bk);
    sk[row][nc + 3] = fmaf(k4.w, wk, bk);
    sv[row][nc + 0] = fmaf(v4.x, wv, bv);
    sv[row][nc + 1] = fmaf(v4.y, wv, bv);
    sv[row][nc + 2] = fmaf(v4.z, wv, bv);
    sv[row][nc + 3] = fmaf(v4.w, wv, bv);
    __syncthreads();

    float* __restrict__ A = ws;
    float* __restrict__ K = ws + (size_t)LL * NN;
    float* __restrict__ V = ws + (size_t)2 * LL * NN;
    const int n = t >> 3, j0 = (t & 7) * 4;  // coalesced: 4 consecutive rows

    float4 o;
    o.x = sa[j0 + 0][n]; o.y = sa[j0 + 1][n]; o.z = sa[j0 + 2][n]; o.w = sa[j0 + 3][n];
    *reinterpret_cast<float4*>(A + (size_t)n * LL + r0 + j0) = o;
    o.x = sk[j0 + 0][n]; o.y = sk[j0 + 1][n]; o.z = sk[j0 + 2][n]; o.w = sk[j0 + 3][n];
    *reinterpret_cast<float4*>(K + (size_t)n * LL + r0 + j0) = o;
    o.x = sv[j0 + 0][n]; o.y = sv[j0 + 1][n]; o.z = sv[j0 + 2][n]; o.w = sv[j0 + 3][n];
    *reinterpret_cast<float4*>(V + (size_t)n * LL + r0 + j0) = o;
}

// deg-10 Horner: coefficients c0..c10 = {f0.xyzw, f1.xyzw, f2.xyz}
__device__ __forceinline__ v2f horner10(v2f u, float4 f0, float4 f1, float4 f2) {
    v2f h = {f2.z, f2.z};
    h = __builtin_elementwise_fma(h, u, (v2f){f2.y, f2.y});
    h = __builtin_elementwise_fma(h, u, (v2f){f2.x, f2.x});
    h = __builtin_elementwise_fma(h, u, (v2f){f1.w, f1.w});
    h = __builtin_elementwise_fma(h, u, (v2f){f1.z, f1.z});
    h = __builtin_elementwise_fma(h, u, (v2f){f1.y, f1.y});
    h = __builtin_elementwise_fma(h, u, (v2f){f1.x, f1.x});
    h = __builtin_elementwise_fma(h, u, (v2f){f0.w, f0.w});
    h = __builtin_elementwise_fma(h, u, (v2f){f0.z, f0.z});
    h = __builtin_elementwise_fma(h, u, (v2f){f0.y, f0.y});
    h = __builtin_elementwise_fma(h, u, (v2f){f0.x, f0.x});
    return h;
}

// ---------------- Kernel A: single-wave, zero barriers, NSEG=8 ----------
__global__ __launch_bounds__(64) void attn_kernel(
    const float* __restrict__ ws,
    const float* __restrict__ opw, const float* __restrict__ opb,
    float* __restrict__ out)
{
    const int lane = threadIdx.x;        // 0..63, one wave per WG
    const int prob = blockIdx.x;         // 0..4095
    const int blk  = prob & 127;         // XCD-aware: siblings same XCD
    const int n    = prob >> 7;

    const float* __restrict__ A = ws;
    const float* __restrict__ K = ws + (size_t)LL * NN;
    const float* __restrict__ V = ws + (size_t)2 * LL * NN;
    const int base = n * LL + blk * BSZ;

    __shared__ alignas(16) float2 skv[BSZ];       // sorted (k, v)
    __shared__ alignas(16) float  mom[NSEG][24];  // D0..10,pad | N0..10,pad
    __shared__ int hist[128];

    // ---- gather: k,v first (sort-critical), a stays in flight ----
    const float4 kf = *reinterpret_cast<const float4*>(K + base + 4 * lane);
    const float4 vf = *reinterpret_cast<const float4*>(V + base + 4 * lane);
    const float4 af = *reinterpret_cast<const float4*>(A + base + 4 * lane);
    float kr[4] = {kf.x, kf.y, kf.z, kf.w};
    float vr[4] = {vf.x, vf.y, vf.z, vf.w};

    // wave kmin/kmax
    float kmn = fminf(fminf(kr[0], kr[1]), fminf(kr[2], kr[3]));
    float kmx = fmaxf(fmaxf(kr[0], kr[1]), fmaxf(kr[2], kr[3]));
    #pragma unroll
    for (int off = 32; off >= 1; off >>= 1) {
        kmn = fminf(kmn, __shfl_xor(kmn, off));
        kmx = fmaxf(kmx, __shfl_xor(kmx, off));
    }
    const float rng  = kmx - kmn;
    const float binv = (rng > 0.f) ? (127.99f / rng) : 0.f;
    const float segw = rng * (1.0f / NSEG);

    // ---- counting sort by 7-bit quantized k (verified; zero barriers) ----
    hist[lane]      = 0;
    hist[lane + 64] = 0;

    int bin[4];
    #pragma unroll
    for (int r = 0; r < 4; ++r) {
        int b = (int)((kr[r] - kmn) * binv);
        bin[r] = (b < 0) ? 0 : ((b > 127) ? 127 : b);
        atomicAdd(&hist[bin[r]], 1);      // wave-private, lane-ordered
    }

    {
        const int c0 = hist[lane];
        const int c1 = hist[lane + 64];
        int i0 = c0, i1 = c1;
        #pragma unroll
        for (int off = 1; off <= 32; off <<= 1) {
            const int t0 = __shfl_up(i0, off);
            const int t1 = __shfl_up(i1, off);
            if (lane >= off) { i0 += t0; i1 += t1; }
        }
        const int tot0 = __shfl(i0, 63);
        hist[lane]      = i0 - c0;        // exclusive starts
        hist[lane + 64] = i1 - c1 + tot0;
    }

    #pragma unroll
    for (int r = 0; r < 4; ++r) {
        const int slot = atomicAdd(&hist[bin[r]], 1);
        skv[slot] = make_float2(kr[r], vr[r]);
    }
    // hist[b] = END offset of bin b

    // ---- moments: 8 lanes per segment (contiguous eighth-ranges) ----
    {
        const int s  = lane >> 3;           // segment 0..7
        const int ee = lane & 7;            // eighth 0..7
        const int beg0 = (s == 0) ? 0 : hist[16 * s - 1];
        const int end0 = hist[16 * s + 15];
        const int len  = end0 - beg0;
        const int beg  = beg0 + (len * ee) / 8;
        const int end  = beg0 + (len * (ee + 1)) / 8;
        const float cs = kmn + (s + 0.5f) * segw;

        float m0=0.f,m1=0.f,m2=0.f,m3=0.f,m4=0.f,m5=0.f,m6=0.f,m7=0.f,m8=0.f,m9=0.f,m10=0.f;
        float q0=0.f,q1=0.f,q2=0.f,q3=0.f,q4=0.f,q5=0.f,q6=0.f,q7=0.f,q8=0.f,q9=0.f,q10=0.f;
        for (int e = beg; e < end; ++e) {
            const float2 kv = skv[e];
            const float dk = kv.x - cs;
            const float vv = kv.y;
            const float p1 = dk,      p2 = p1 * dk, p3 = p2 * dk, p4 = p3 * dk;
            const float p5 = p4 * dk, p6 = p5 * dk, p7 = p6 * dk, p8 = p7 * dk;
            const float p9 = p8 * dk, pA = p9 * dk;
            m0 += 1.f; m1 += p1; m2 += p2; m3 += p3; m4 += p4; m5 += p5;
            m6 += p6;  m7 += p7; m8 += p8; m9 += p9; m10 += pA;
            q0 += vv;
            q1 = fmaf(vv, p1, q1); q2 = fmaf(vv, p2, q2); q3 = fmaf(vv, p3, q3);
            q4 = fmaf(vv, p4, q4); q5 = fmaf(vv, p5, q5); q6 = fmaf(vv, p6, q6);
            q7 = fmaf(vv, p7, q7); q8 = fmaf(vv, p8, q8); q9 = fmaf(vv, p9, q9);
            q10 = fmaf(vv, pA, q10);
        }
        // combine 8 eighths (aligned 8-lane groups)
        #pragma unroll
        for (int off = 1; off <= 4; off <<= 1) {
            m0 += __shfl_xor(m0, off); m1 += __shfl_xor(m1, off);
            m2 += __shfl_xor(m2, off); m3 += __shfl_xor(m3, off);
            m4 += __shfl_xor(m4, off); m5 += __shfl_xor(m5, off);
            m6 += __shfl_xor(m6, off); m7 += __shfl_xor(m7, off);
            m8 += __shfl_xor(m8, off); m9 += __shfl_xor(m9, off);
            m10 += __shfl_xor(m10, off);
            q0 += __shfl_xor(q0, off); q1 += __shfl_xor(q1, off);
            q2 += __shfl_xor(q2, off); q3 += __shfl_xor(q3, off);
            q4 += __shfl_xor(q4, off); q5 += __shfl_xor(q5, off);
            q6 += __shfl_xor(q6, off); q7 += __shfl_xor(q7, off);
            q8 += __shfl_xor(q8, off); q9 += __shfl_xor(q9, off);
            q10 += __shfl_xor(q10, off);
        }
        // 6 float4 per segment, written by lanes ee=0..5
        float4 wv4;
        bool doW = true;
        if (ee == 0)      wv4 = make_float4(m0, m1, m2 * 0.5f, m3 * (1.f/6.f));
        else if (ee == 1) wv4 = make_float4(m4 * (1.f/24.f), m5 * (1.f/120.f),
                                            m6 * (1.f/720.f), m7 * (1.f/5040.f));
        else if (ee == 2) wv4 = make_float4(m8 * (1.f/40320.f), m9 * (1.f/362880.f),
                                            m10 * (1.f/3628800.f), 0.f);
        else if (ee == 3) wv4 = make_float4(q0, q1, q2 * 0.5f, q3 * (1.f/6.f));
        else if (ee == 4) wv4 = make_float4(q4 * (1.f/24.f), q5 * (1.f/120.f),
                                            q6 * (1.f/720.f), q7 * (1.f/5040.f));
        else if (ee == 5) wv4 = make_float4(q8 * (1.f/40320.f), q9 * (1.f/362880.f),
                                            q10 * (1.f/3628800.f), 0.f);
        else doW = false;
        if (doW)
            *reinterpret_cast<float4*>(&mom[s][ee * 4]) = wv4;
    }

    // ---- row loop: 4 rows/thread, E-recurrence (2 chains), deg-10 Horner ----
    const float a[4] = {af.x, af.y, af.z, af.w};   // already * LOG2E
    const v2f u01 = {a[0] * LN2, a[1] * LN2};
    const v2f u23 = {a[2] * LN2, a[3] * LN2};
    const float c0s = kmn + 0.5f * segw;

    v2f Ee01, Ee23, g01, g23;
    Ee01.x = __builtin_amdgcn_exp2f(a[0] * c0s);
    Ee01.y = __builtin_amdgcn_exp2f(a[1] * c0s);
    Ee23.x = __builtin_amdgcn_exp2f(a[2] * c0s);
    Ee23.y = __builtin_amdgcn_exp2f(a[3] * c0s);
    g01.x  = __builtin_amdgcn_exp2f(a[0] * segw);
    g01.y  = __builtin_amdgcn_exp2f(a[1] * segw);
    g23.x  = __builtin_amdgcn_exp2f(a[2] * segw);
    g23.y  = __builtin_amdgcn_exp2f(a[3] * segw);
    const v2f G2_01 = g01 * g01;
    const v2f G2_23 = g23 * g23;
    v2f Eo01 = Ee01 * g01;
    v2f Eo23 = Ee23 * g23;

    v2f de01 = {0.f,0.f}, do01 = {0.f,0.f}, de23 = {0.f,0.f}, do23 = {0.f,0.f};
    v2f ne01 = {0.f,0.f}, no01 = {0.f,0.f}, ne23 = {0.f,0.f}, no23 = {0.f,0.f};

    const float4* __restrict__ M4 = (const float4*)&mom[0][0];  // 6 per seg

    #pragma unroll 4
    for (int s = 0; s < NSEG; s += 2) {
        {   // even segment
            const float4 f0 = M4[s * 6 + 0];
            const float4 f1 = M4[s * 6 + 1];
            const float4 f2 = M4[s * 6 + 2];
            const float4 f3 = M4[s * 6 + 3];
            const float4 f4 = M4[s * 6 + 4];
            const float4 f5 = M4[s * 6 + 5];
            const v2f hd01 = horner10(u01, f0, f1, f2);
            const v2f hn01 = horner10(u01, f3, f4, f5);
            const v2f hd23 = horner10(u23, f0, f1, f2);
            const v2f hn23 = horner10(u23, f3, f4, f5);
            de01 = __builtin_elementwise_fma(Ee01, hd01, de01);
            ne01 = __builtin_elementwise_fma(Ee01, hn01, ne01);
            de23 = __builtin_elementwise_fma(Ee23, hd23, de23);
            ne23 = __builtin_elementwise_fma(Ee23, hn23, ne23);
            Ee01 = Ee01 * G2_01;
            Ee23 = Ee23 * G2_23;
        }
        {   // odd segment
            const float4 f0 = M4[(s + 1) * 6 + 0];
            const float4 f1 = M4[(s + 1) * 6 + 1];
            const float4 f2 = M4[(s + 1) * 6 + 2];
            const float4 f3 = M4[(s + 1) * 6 + 3];
            const float4 f4 = M4[(s + 1) * 6 + 4];
            const float4 f5 = M4[(s + 1) * 6 + 5];
            const v2f hd01 = horner10(u01, f0, f1, f2);
            const v2f hn01 = horner10(u01, f3, f4, f5);
            const v2f hd23 = horner10(u23, f0, f1, f2);
            const v2f hn23 = horner10(u23, f3, f4, f5);
            do01 = __builtin_elementwise_fma(Eo01, hd01, do01);
            no01 = __builtin_elementwise_fma(Eo01, hn01, no01);
            do23 = __builtin_elementwise_fma(Eo23, hd23, do23);
            no23 = __builtin_elementwise_fma(Eo23, hn23, no23);
            Eo01 = Eo01 * G2_01;
            Eo23 = Eo23 * G2_23;
        }
    }

    const v2f den01 = de01 + do01, den23 = de23 + do23;
    const v2f num01 = ne01 + no01, num23 = ne23 + no23;

    const float wo = opw[0], bo = opb[0];
    const int rbase = blk * BSZ + 4 * lane;
    out[(size_t)(rbase + 0) * NN + n] = fmaf(num01.x / den01.x, wo, bo);
    out[(size_t)(rbase + 1) * NN + n] = fmaf(num01.y / den01.y, wo, bo);
    out[(size_t)(rbase + 2) * NN + n] = fmaf(num23.x / den23.x, wo, bo);
    out[(size_t)(rbase + 3) * NN + n] = fmaf(num23.y / den23.y, wo, bo);
}

extern "C" void kernel_launch(void* const* d_in, const int* in_sizes, int n_in,
                              void* d_out, int out_size, void* d_ws, size_t ws_size,
                              hipStream_t stream) {
    const float* q   = (const float*)d_in[0];
    const float* k   = (const float*)d_in[1];
    const float* v   = (const float*)d_in[2];
    const float* ipw = (const float*)d_in[3];
    const float* ipb = (const float*)d_in[4];
    const float* opw = (const float*)d_in[5];
    const float* opb = (const float*)d_in[6];
    float* out = (float*)d_out;
    float* ws  = (float*)d_ws;   // needs 3*L*N*4 = 12.6 MB

    proj_transpose_kernel<<<dim3(LL / 32), dim3(256), 0, stream>>>(q, k, v, ipw, ipb, ws);
    attn_kernel<<<dim3(NBLK * NN), dim3(64), 0, stream>>>(ws, opw, opb, out);
}

// Round 30
// 17.839 us; speedup vs baseline: 1.2914x; 1.2211x over previous
//
#include <hip/hip_runtime.h>

// L=32768, N=32, E=H=1, BS=256 -> 4096 rank-1 softmax problems:
//   out_i = sum_j 2^(a'_i k_j) v_j / sum_j 2^(a'_i k_j),  a' = (wq q + bq) log2e.
// No max-subtraction (f32-safe, scale-invariant; validated R5-R29).
//
// R30 = R29 (21.8us) with the prepass FUSED: one WG = 4 waves = 4 problems
// (blk, n0..n0+3). Threads cooperatively load [256 rows x 4 batches] float4
// tiles from the ORIGINAL q/k/v (16B/lane; 8 sibling WGs of a blk share the
// 128B lines in the same XCD L2), project, and write TRANSPOSED to LDS
// (bank-conflict-free). ONE barrier; then each wave runs the complete R29
// pipeline privately (own skv/hist/mom, no further barriers -- shared staging
// only, unlike R17/R20/R24 which shared computation and lost).
// Removes: prepass kernel (~4.3us), 25MB ws round-trip, inter-kernel gap.

#define LL    32768
#define NN    32
#define BSZ   256
#define NBLK  (LL / BSZ)
#define NSEG  8
#define LOG2E 1.4426950408889634f
#define LN2   0.6931471805599453f

typedef float v2f __attribute__((ext_vector_type(2)));

// deg-10 Horner: coefficients c0..c10 = {f0.xyzw, f1.xyzw, f2.xyz}
__device__ __forceinline__ v2f horner10(v2f u, float4 f0, float4 f1, float4 f2) {
    v2f h = {f2.z, f2.z};
    h = __builtin_elementwise_fma(h, u, (v2f){f2.y, f2.y});
    h = __builtin_elementwise_fma(h, u, (v2f){f2.x, f2.x});
    h = __builtin_elementwise_fma(h, u, (v2f){f1.w, f1.w});
    h = __builtin_elementwise_fma(h, u, (v2f){f1.z, f1.z});
    h = __builtin_elementwise_fma(h, u, (v2f){f1.y, f1.y});
    h = __builtin_elementwise_fma(h, u, (v2f){f1.x, f1.x});
    h = __builtin_elementwise_fma(h, u, (v2f){f0.w, f0.w});
    h = __builtin_elementwise_fma(h, u, (v2f){f0.z, f0.z});
    h = __builtin_elementwise_fma(h, u, (v2f){f0.y, f0.y});
    h = __builtin_elementwise_fma(h, u, (v2f){f0.x, f0.x});
    return h;
}

__global__ __launch_bounds__(256) void BlockCrossAttn_kernel(
    const float* __restrict__ q_in, const float* __restrict__ k_in,
    const float* __restrict__ v_in,
    const float* __restrict__ ipw,  const float* __restrict__ ipb,
    const float* __restrict__ opw,  const float* __restrict__ opb,
    float* __restrict__ out)
{
    const int t    = threadIdx.x;        // 0..255
    const int lane = t & 63;
    const int w    = t >> 6;             // wave 0..3 -> problem (blk, n0+w)
    const int g    = blockIdx.x;         // 0..1023
    const int blk  = g & 127;            // XCD-aware: siblings same XCD
    const int n0   = (g >> 7) << 2;      // 0,4,...,28

    __shared__ alignas(16) float  sA[4][BSZ];     // staged, transposed [j][row]
    __shared__ alignas(16) float  sK[4][BSZ];
    __shared__ alignas(16) float  sV[4][BSZ];
    __shared__ alignas(16) float2 skv[4][BSZ];    // per-wave sorted (k,v)
    __shared__ alignas(16) float  mom[4][NSEG][24];
    __shared__ int hist[4][128];

    // ---- cooperative staging: thread t = row t, 4 batches n0..n0+3 ----
    {
        const float wq = ipw[0], wk = ipw[1], wv = ipw[2];
        const float bq = ipb[0], bk = ipb[1], bv = ipb[2];
        const int f = (blk * BSZ + t) * NN + n0;       // 16B aligned
        const float4 q4 = *reinterpret_cast<const float4*>(q_in + f);
        const float4 k4 = *reinterpret_cast<const float4*>(k_in + f);
        const float4 v4 = *reinterpret_cast<const float4*>(v_in + f);
        sA[0][t] = fmaf(q4.x, wq, bq) * LOG2E;
        sA[1][t] = fmaf(q4.y, wq, bq) * LOG2E;
        sA[2][t] = fmaf(q4.z, wq, bq) * LOG2E;
        sA[3][t] = fmaf(q4.w, wq, bq) * LOG2E;
        sK[0][t] = fmaf(k4.x, wk, bk);
        sK[1][t] = fmaf(k4.y, wk, bk);
        sK[2][t] = fmaf(k4.z, wk, bk);
        sK[3][t] = fmaf(k4.w, wk, bk);
        sV[0][t] = fmaf(v4.x, wv, bv);
        sV[1][t] = fmaf(v4.y, wv, bv);
        sV[2][t] = fmaf(v4.z, wv, bv);
        sV[3][t] = fmaf(v4.w, wv, bv);
    }
    __syncthreads();   // ONLY barrier: staging -> per-wave private pipelines

    // ---- per-wave private from here (zero further barriers) ----
    const float4 af = *reinterpret_cast<const float4*>(&sA[w][4 * lane]);
    const float4 kf = *reinterpret_cast<const float4*>(&sK[w][4 * lane]);
    const float4 vf = *reinterpret_cast<const float4*>(&sV[w][4 * lane]);
    float kr[4] = {kf.x, kf.y, kf.z, kf.w};
    float vr[4] = {vf.x, vf.y, vf.z, vf.w};

    // wave kmin/kmax
    float kmn = fminf(fminf(kr[0], kr[1]), fminf(kr[2], kr[3]));
    float kmx = fmaxf(fmaxf(kr[0], kr[1]), fmaxf(kr[2], kr[3]));
    #pragma unroll
    for (int off = 32; off >= 1; off >>= 1) {
        kmn = fminf(kmn, __shfl_xor(kmn, off));
        kmx = fmaxf(kmx, __shfl_xor(kmx, off));
    }
    const float rng  = kmx - kmn;
    const float binv = (rng > 0.f) ? (127.99f / rng) : 0.f;
    const float segw = rng * (1.0f / NSEG);

    // ---- counting sort by 7-bit quantized k (wave-private, no barriers) ----
    hist[w][lane]      = 0;
    hist[w][lane + 64] = 0;

    int bin[4];
    #pragma unroll
    for (int r = 0; r < 4; ++r) {
        int b = (int)((kr[r] - kmn) * binv);
        bin[r] = (b < 0) ? 0 : ((b > 127) ? 127 : b);
        atomicAdd(&hist[w][bin[r]], 1);   // wave-private, lane-ordered
    }

    {
        const int c0 = hist[w][lane];
        const int c1 = hist[w][lane + 64];
        int i0 = c0, i1 = c1;
        #pragma unroll
        for (int off = 1; off <= 32; off <<= 1) {
            const int t0 = __shfl_up(i0, off);
            const int t1 = __shfl_up(i1, off);
            if (lane >= off) { i0 += t0; i1 += t1; }
        }
        const int tot0 = __shfl(i0, 63);
        hist[w][lane]      = i0 - c0;     // exclusive starts
        hist[w][lane + 64] = i1 - c1 + tot0;
    }

    #pragma unroll
    for (int r = 0; r < 4; ++r) {
        const int slot = atomicAdd(&hist[w][bin[r]], 1);
        skv[w][slot] = make_float2(kr[r], vr[r]);
    }
    // hist[w][b] = END offset of bin b

    // ---- moments: 8 lanes per segment (contiguous eighth-ranges) ----
    {
        const int s  = lane >> 3;           // segment 0..7
        const int ee = lane & 7;            // eighth 0..7
        const int beg0 = (s == 0) ? 0 : hist[w][16 * s - 1];
        const int end0 = hist[w][16 * s + 15];
        const int len  = end0 - beg0;
        const int beg  = beg0 + (len * ee) / 8;
        const int end  = beg0 + (len * (ee + 1)) / 8;
        const float cs = kmn + (s + 0.5f) * segw;

        float m0=0.f,m1=0.f,m2=0.f,m3=0.f,m4=0.f,m5=0.f,m6=0.f,m7=0.f,m8=0.f,m9=0.f,m10=0.f;
        float q0=0.f,q1=0.f,q2=0.f,q3=0.f,q4=0.f,q5=0.f,q6=0.f,q7=0.f,q8=0.f,q9=0.f,q10=0.f;
        for (int e = beg; e < end; ++e) {
            const float2 kv = skv[w][e];
            const float dk = kv.x - cs;
            const float vv = kv.y;
            const float p1 = dk,      p2 = p1 * dk, p3 = p2 * dk, p4 = p3 * dk;
            const float p5 = p4 * dk, p6 = p5 * dk, p7 = p6 * dk, p8 = p7 * dk;
            const float p9 = p8 * dk, pA = p9 * dk;
            m0 += 1.f; m1 += p1; m2 += p2; m3 += p3; m4 += p4; m5 += p5;
            m6 += p6;  m7 += p7; m8 += p8; m9 += p9; m10 += pA;
            q0 += vv;
            q1 = fmaf(vv, p1, q1); q2 = fmaf(vv, p2, q2); q3 = fmaf(vv, p3, q3);
            q4 = fmaf(vv, p4, q4); q5 = fmaf(vv, p5, q5); q6 = fmaf(vv, p6, q6);
            q7 = fmaf(vv, p7, q7); q8 = fmaf(vv, p8, q8); q9 = fmaf(vv, p9, q9);
            q10 = fmaf(vv, pA, q10);
        }
        // combine 8 eighths (aligned 8-lane groups)
        #pragma unroll
        for (int off = 1; off <= 4; off <<= 1) {
            m0 += __shfl_xor(m0, off); m1 += __shfl_xor(m1, off);
            m2 += __shfl_xor(m2, off); m3 += __shfl_xor(m3, off);
            m4 += __shfl_xor(m4, off); m5 += __shfl_xor(m5, off);
            m6 += __shfl_xor(m6, off); m7 += __shfl_xor(m7, off);
            m8 += __shfl_xor(m8, off); m9 += __shfl_xor(m9, off);
            m10 += __shfl_xor(m10, off);
            q0 += __shfl_xor(q0, off); q1 += __shfl_xor(q1, off);
            q2 += __shfl_xor(q2, off); q3 += __shfl_xor(q3, off);
            q4 += __shfl_xor(q4, off); q5 += __shfl_xor(q5, off);
            q6 += __shfl_xor(q6, off); q7 += __shfl_xor(q7, off);
            q8 += __shfl_xor(q8, off); q9 += __shfl_xor(q9, off);
            q10 += __shfl_xor(q10, off);
        }
        // 6 float4 per segment, written by lanes ee=0..5
        float4 wv4;
        bool doW = true;
        if (ee == 0)      wv4 = make_float4(m0, m1, m2 * 0.5f, m3 * (1.f/6.f));
        else if (ee == 1) wv4 = make_float4(m4 * (1.f/24.f), m5 * (1.f/120.f),
                                            m6 * (1.f/720.f), m7 * (1.f/5040.f));
        else if (ee == 2) wv4 = make_float4(m8 * (1.f/40320.f), m9 * (1.f/362880.f),
                                            m10 * (1.f/3628800.f), 0.f);
        else if (ee == 3) wv4 = make_float4(q0, q1, q2 * 0.5f, q3 * (1.f/6.f));
        else if (ee == 4) wv4 = make_float4(q4 * (1.f/24.f), q5 * (1.f/120.f),
                                            q6 * (1.f/720.f), q7 * (1.f/5040.f));
        else if (ee == 5) wv4 = make_float4(q8 * (1.f/40320.f), q9 * (1.f/362880.f),
                                            q10 * (1.f/3628800.f), 0.f);
        else doW = false;
        if (doW)
            *reinterpret_cast<float4*>(&mom[w][s][ee * 4]) = wv4;
    }

    // ---- row loop: 4 rows/thread, E-recurrence (2 chains), deg-10 Horner ----
    const float a[4] = {af.x, af.y, af.z, af.w};   // already * LOG2E
    const v2f u01 = {a[0] * LN2, a[1] * LN2};
    const v2f u23 = {a[2] * LN2, a[3] * LN2};
    const float c0s = kmn + 0.5f * segw;

    v2f Ee01, Ee23, g01, g23;
    Ee01.x = __builtin_amdgcn_exp2f(a[0] * c0s);
    Ee01.y = __builtin_amdgcn_exp2f(a[1] * c0s);
    Ee23.x = __builtin_amdgcn_exp2f(a[2] * c0s);
    Ee23.y = __builtin_amdgcn_exp2f(a[3] * c0s);
    g01.x  = __builtin_amdgcn_exp2f(a[0] * segw);
    g01.y  = __builtin_amdgcn_exp2f(a[1] * segw);
    g23.x  = __builtin_amdgcn_exp2f(a[2] * segw);
    g23.y  = __builtin_amdgcn_exp2f(a[3] * segw);
    const v2f G2_01 = g01 * g01;
    const v2f G2_23 = g23 * g23;
    v2f Eo01 = Ee01 * g01;
    v2f Eo23 = Ee23 * g23;

    v2f de01 = {0.f,0.f}, do01 = {0.f,0.f}, de23 = {0.f,0.f}, do23 = {0.f,0.f};
    v2f ne01 = {0.f,0.f}, no01 = {0.f,0.f}, ne23 = {0.f,0.f}, no23 = {0.f,0.f};

    const float4* __restrict__ M4 = (const float4*)&mom[w][0][0];  // 6 per seg

    #pragma unroll 4
    for (int s = 0; s < NSEG; s += 2) {
        {   // even segment
            const float4 f0 = M4[s * 6 + 0];
            const float4 f1 = M4[s * 6 + 1];
            const float4 f2 = M4[s * 6 + 2];
            const float4 f3 = M4[s * 6 + 3];
            const float4 f4 = M4[s * 6 + 4];
            const float4 f5 = M4[s * 6 + 5];
            const v2f hd01 = horner10(u01, f0, f1, f2);
            const v2f hn01 = horner10(u01, f3, f4, f5);
            const v2f hd23 = horner10(u23, f0, f1, f2);
            const v2f hn23 = horner10(u23, f3, f4, f5);
            de01 = __builtin_elementwise_fma(Ee01, hd01, de01);
            ne01 = __builtin_elementwise_fma(Ee01, hn01, ne01);
            de23 = __builtin_elementwise_fma(Ee23, hd23, de23);
            ne23 = __builtin_elementwise_fma(Ee23, hn23, ne23);
            Ee01 = Ee01 * G2_01;
            Ee23 = Ee23 * G2_23;
        }
        {   // odd segment
            const float4 f0 = M4[(s + 1) * 6 + 0];
            const float4 f1 = M4[(s + 1) * 6 + 1];
            const float4 f2 = M4[(s + 1) * 6 + 2];
            const float4 f3 = M4[(s + 1) * 6 + 3];
            const float4 f4 = M4[(s + 1) * 6 + 4];
            const float4 f5 = M4[(s + 1) * 6 + 5];
            const v2f hd01 = horner10(u01, f0, f1, f2);
            const v2f hn01 = horner10(u01, f3, f4, f5);
            const v2f hd23 = horner10(u23, f0, f1, f2);
            const v2f hn23 = horner10(u23, f3, f4, f5);
            do01 = __builtin_elementwise_fma(Eo01, hd01, do01);
            no01 = __builtin_elementwise_fma(Eo01, hn01, no01);
            do23 = __builtin_elementwise_fma(Eo23, hd23, do23);
            no23 = __builtin_elementwise_fma(Eo23, hn23, no23);
            Eo01 = Eo01 * G2_01;
            Eo23 = Eo23 * G2_23;
        }
    }

    const v2f den01 = de01 + do01, den23 = de23 + do23;
    const v2f num01 = ne01 + no01, num23 = ne23 + no23;

    const float wo = opw[0], bo = opb[0];
    const int n = n0 + w;
    const int rbase = blk * BSZ + 4 * lane;
    out[(size_t)(rbase + 0) * NN + n] = fmaf(num01.x / den01.x, wo, bo);
    out[(size_t)(rbase + 1) * NN + n] = fmaf(num01.y / den01.y, wo, bo);
    out[(size_t)(rbase + 2) * NN + n] = fmaf(num23.x / den23.x, wo, bo);
    out[(size_t)(rbase + 3) * NN + n] = fmaf(num23.y / den23.y, wo, bo);
}

extern "C" void kernel_launch(void* const* d_in, const int* in_sizes, int n_in,
                              void* d_out, int out_size, void* d_ws, size_t ws_size,
                              hipStream_t stream) {
    const float* q   = (const float*)d_in[0];
    const float* k   = (const float*)d_in[1];
    const float* v   = (const float*)d_in[2];
    const float* ipw = (const float*)d_in[3];
    const float* ipb = (const float*)d_in[4];
    const float* opw = (const float*)d_in[5];
    const float* opb = (const float*)d_in[6];
    float* out = (float*)d_out;

    // 1024 WGs x 256 threads: WG = (blk, n0..n0+3), one wave per problem.
    BlockCrossAttn_kernel<<<dim3(NBLK * NN / 4), dim3(256), 0, stream>>>(
        q, k, v, ipw, ipb, opw, opb, out);
}